// Round 12
// baseline (71.973 us; speedup 1.0000x reference)
//
#include <hip/hip_runtime.h>

#define HH 192
#define WW 192
#define BB 2
#define NC 6
#define FSZ 11
#define PAD 5
#define TC 64              // tile cols
#define TR 2               // tile rows
#define SR 12              // staged rows = TR + 2*PAD
#define SC 75              // staged cols = TC + 2*PAD + 1 (j=11 pad-tap guard)
#define HW (HH*WW)
#define NPX (TC*TR)        // 128 px per block
#define JW 12              // tf j-stride (11 taps + 1 zero pad)
#define TF_PER_BLK ((size_t)FSZ*NPX*JW)   // 16896 floats per block

// bf16 pack/unpack (round-half-up)
__device__ __forceinline__ unsigned pkbf(float a, float b) {
    unsigned ua = (__float_as_uint(a) + 0x8000u) >> 16;
    unsigned ub = (__float_as_uint(b) + 0x8000u) & 0xffff0000u;
    return ua | ub;
}
__device__ __forceinline__ float lo16(unsigned u){ return __uint_as_float(u << 16); }
__device__ __forceinline__ float hi16(unsigned u){ return __uint_as_float(u & 0xffff0000u); }

// ---------------------------------------------------------------------------
// Precompute total_filter, px-minor j-vectorized layout:
//   tf[blk][i][px][j 0..11]  (j=11 slot = 0)
// tf = sf(i,j) * (sw + aw * exp(-|fs(p)-fs(p+d)|^2)), fs prescaled by
// iab*sqrt(0.5). Iteration-invariant. Also writes q0 = softmax(x) slab.
// Tile 64x2, 4 waves: wave = (gx = tile row, ih = i-half {0..5 / 6..10}).
// ---------------------------------------------------------------------------
__global__ __launch_bounds__(256, 2)
void crf_tf(const float* __restrict__ xpl, const float* __restrict__ feats,
            const float* __restrict__ spac, const float* __restrict__ swp,
            const float* __restrict__ awp, const float* __restrict__ isbp,
            const float* __restrict__ iabp,
            float* __restrict__ tf, uint4* __restrict__ A0)
{
    __shared__ float2 F01[SR][SC];
    __shared__ float  F2s[SR][SC];
    __shared__ float  sfw[FSZ*FSZ], sfa[FSZ*FSZ];

    const int tid = threadIdx.x;
    const int b  = blockIdx.z;
    const int c0 = blockIdx.x * TC;
    const int h0 = blockIdx.y * TR;
    const int blk = (b * gridDim.y + blockIdx.y) * gridDim.x + blockIdx.x;

    const float sw = swp[0], aw = awp[0], isb = isbp[0], iab = iabp[0];
    const float s0 = spac[b*2], s1 = spac[b*2+1];
    const float sfac = iab * 0.70710678f;

    if (tid < FSZ*FSZ) {
        const int fi = tid / FSZ, fj = tid - (tid/FSZ)*FSZ;
        const float ri = (float)(fi-PAD)*s0*isb;
        const float rj = (float)(fj-PAD)*s1*isb;
        float sf = __expf(-0.5f*(ri*ri+rj*rj));
        if (fi==PAD && fj==PAD) sf = 0.f;
        sfw[tid] = sf*sw; sfa[tid] = sf*aw;
    }

    const float* fb = feats + (size_t)b*3*HW;
    for (int idx = tid; idx < SR*SC; idx += 256) {
        const int sr = idx / SC, sc = idx - (idx/SC)*SC;
        const int gh = h0 + sr - PAD, gw = c0 + sc - PAD;
        float g0=0.f,g1=0.f,g2=0.f;
        if (gh>=0 && gh<HH && gw>=0 && gw<WW) {
            const int off = gh*WW+gw;
            g0 = fb[off]*sfac; g1 = fb[off+HW]*sfac; g2 = fb[off+2*HW]*sfac;
        }
        F01[sr][sc] = make_float2(g0,g1);
        F2s[sr][sc] = g2;
    }
    __syncthreads();

    const int w  = tid >> 6;
    const int l  = tid & 63;
    const int gx = w & 1;          // tile row
    const int ih = w >> 1;         // i-half
    const int px = gx*64 + l;

    const float cf0 = F01[gx+PAD][l+PAD].x;
    const float cf1 = F01[gx+PAD][l+PAD].y;
    const float cf2 = F2s[gx+PAD][l+PAD];

    const int i0 = ih ? 6 : 0, i1 = ih ? FSZ : 6;
    #pragma unroll 1
    for (int i = i0; i < i1; ++i) {
        float o[JW];
        #pragma unroll
        for (int j = 0; j < FSZ; ++j) {
            const float2 g01 = F01[gx+i][l+j];
            const float  g2v = F2s[gx+i][l+j];
            const float d0 = cf0-g01.x, d1 = cf1-g01.y, d2 = cf2-g2v;
            const float t = fmaf(d2,d2, fmaf(d1,d1, d0*d0));
            o[j] = fmaf(__expf(-t), sfa[i*FSZ+j], sfw[i*FSZ+j]);
        }
        o[11] = 0.f;
        float4* dst = (float4*)(tf + ((size_t)blk*FSZ + i)*NPX*JW + (size_t)px*JW);
        dst[0] = make_float4(o[0],o[1],o[2],o[3]);
        dst[1] = make_float4(o[4],o[5],o[6],o[7]);
        dst[2] = make_float4(o[8],o[9],o[10],o[11]);
    }

    // q0 = softmax(x) for this block's 128 px (px-major packed slab)
    if (tid < NPX) {
        const int h = h0 + (tid>>6), wc = c0 + (tid&63);
        const float* xb = xpl + (size_t)b*NC*HW + h*WW + wc;
        const float v0=xb[0],v1=xb[HW],v2=xb[2*HW],v3=xb[3*HW],v4=xb[4*HW],v5=xb[5*HW];
        float m = fmaxf(fmaxf(fmaxf(v0,v1),fmaxf(v2,v3)),fmaxf(v4,v5));
        float q0=__expf(v0-m),q1=__expf(v1-m),q2=__expf(v2-m);
        float q3=__expf(v3-m),q4=__expf(v4-m),q5=__expf(v5-m);
        const float rs = 1.0f/(q0+q1+q2+q3+q4+q5);
        A0[(size_t)(b*HH+h)*WW + wc] =
            make_uint4(pkbf(q0*rs,q1*rs), pkbf(q2*rs,q3*rs), pkbf(q4*rs,q5*rs), 0u);
    }
}

// ---------------------------------------------------------------------------
// One mean-field iteration with precomputed tf. Per tap: 1 b128 LDS (q) +
// 1/4 dwordx4 (tf, 48B contiguous per lane-row) + 6 unpack + 6 fma. No exp.
// ---------------------------------------------------------------------------
template<bool LAST>
__global__ __launch_bounds__(256, 4)
void crf_it(const float* __restrict__ xpl, const uint4* __restrict__ Ain,
            const float* __restrict__ tf,
            uint4* __restrict__ Aout, float* __restrict__ outp)
{
    __shared__ uint4 A[SR][SC];          // q01,q23,q45 (bf16x2), .w unused
    __shared__ float pm[2][TR][NC][64];  // partial msgs [ih][gx][c][lane]

    const int tid = threadIdx.x;
    const int b  = blockIdx.z;
    const int c0 = blockIdx.x * TC;
    const int h0 = blockIdx.y * TR;
    const int blk = (b * gridDim.y + blockIdx.y) * gridDim.x + blockIdx.x;

    // stage q tile + halo (zeros outside image)
    for (int idx = tid; idx < SR*SC; idx += 256) {
        const int sr = idx / SC, sc = idx - (idx/SC)*SC;
        const int gh = h0 + sr - PAD, gw = c0 + sc - PAD;
        uint4 av = make_uint4(0u,0u,0u,0u);
        if (gh>=0 && gh<HH && gw>=0 && gw<WW)
            av = Ain[(size_t)(b*HH+gh)*WW + gw];
        A[sr][sc] = av;
    }
    __syncthreads();

    const int w  = tid >> 6;
    const int l  = tid & 63;
    const int gx = w & 1;
    const int ih = w >> 1;
    const int px = gx*64 + l;

    float msg[NC];
    #pragma unroll
    for (int c = 0; c < NC; ++c) msg[c] = 0.f;

    const int i0 = ih ? 6 : 0, i1 = ih ? FSZ : 6;
    #pragma unroll 1
    for (int i = i0; i < i1; ++i) {
        const float4* tp = (const float4*)(tf + ((size_t)blk*FSZ + i)*NPX*JW + (size_t)px*JW);
        const float4 t0 = tp[0], t1 = tp[1], t2 = tp[2];
        const float tfv[JW] = {t0.x,t0.y,t0.z,t0.w, t1.x,t1.y,t1.z,t1.w,
                               t2.x,t2.y,t2.z,t2.w};
        const uint4* Ar = &A[gx+i][l];
        #pragma unroll
        for (int j = 0; j < JW; ++j) {        // j=11: tfv=0, dead tap
            const uint4 qv = Ar[j];
            const float tv = tfv[j];
            msg[0] = fmaf(tv, lo16(qv.x), msg[0]);
            msg[1] = fmaf(tv, hi16(qv.x), msg[1]);
            msg[2] = fmaf(tv, lo16(qv.y), msg[2]);
            msg[3] = fmaf(tv, hi16(qv.y), msg[3]);
            msg[4] = fmaf(tv, lo16(qv.z), msg[4]);
            msg[5] = fmaf(tv, hi16(qv.z), msg[5]);
        }
    }

    #pragma unroll
    for (int c = 0; c < NC; ++c) pm[ih][gx][c][l] = msg[c];
    __syncthreads();

    // epilogue: 128 threads, one px each
    if (tid < NPX) {
        const int gy = tid >> 6, lc = tid & 63;
        const int h = h0 + gy, wc = c0 + lc;
        const size_t pb = (size_t)b*NC*HW + (size_t)h*WW + wc;
        float xn[NC];
        #pragma unroll
        for (int c = 0; c < NC; ++c)
            xn[c] = pm[0][gy][c][lc] + pm[1][gy][c][lc] + xpl[pb + (size_t)c*HW];

        float m = xn[0];
        #pragma unroll
        for (int c = 1; c < NC; ++c) m = fmaxf(m, xn[c]);

        if (LAST) {
            float s = 0.f;
            #pragma unroll
            for (int c = 0; c < NC; ++c) s += __expf(xn[c]-m);
            const float lg = m + __logf(s);
            #pragma unroll
            for (int c = 0; c < NC; ++c) outp[pb + (size_t)c*HW] = xn[c] - lg;
        } else {
            float e[NC], s = 0.f;
            #pragma unroll
            for (int c = 0; c < NC; ++c) { e[c] = __expf(xn[c]-m); s += e[c]; }
            const float rs = 1.0f / s;
            Aout[(size_t)(b*HH+h)*WW + wc] =
                make_uint4(pkbf(e[0]*rs,e[1]*rs), pkbf(e[2]*rs,e[3]*rs),
                           pkbf(e[4]*rs,e[5]*rs), 0u);
        }
    }
}

extern "C" void kernel_launch(void* const* d_in, const int* in_sizes, int n_in,
                              void* d_out, int out_size, void* d_ws, size_t ws_size,
                              hipStream_t stream)
{
    const float* x    = (const float*)d_in[0];
    const float* fts  = (const float*)d_in[1];
    const float* spc  = (const float*)d_in[2];
    const float* swp  = (const float*)d_in[3];
    const float* awp  = (const float*)d_in[4];
    const float* isbp = (const float*)d_in[5];
    const float* iabp = (const float*)d_in[6];
    float* out = (float*)d_out;

    const int nblk = (WW/TC) * (HH/TR) * BB;               // 576
    float* tf = (float*)d_ws;                              // 38.9 MB
    uint4* A0 = (uint4*)((char*)d_ws + (size_t)nblk*TF_PER_BLK*sizeof(float));
    uint4* A1 = A0 + (size_t)BB*HW;                        // 1.18 MB each

    dim3 grid(WW/TC, HH/TR, BB);   // 3 x 96 x 2 = 576 blocks
    dim3 blk(256);                 // 4 waves

    crf_tf<<<grid, blk, 0, stream>>>(x, fts, spc, swp, awp, isbp, iabp, tf, A0);
    crf_it<false><<<grid, blk, 0, stream>>>(x, A0, tf, A1, out);
    crf_it<false><<<grid, blk, 0, stream>>>(x, A1, tf, A0, out);
    crf_it<false><<<grid, blk, 0, stream>>>(x, A0, tf, A1, out);
    crf_it<false><<<grid, blk, 0, stream>>>(x, A1, tf, A0, out);
    crf_it<true ><<<grid, blk, 0, stream>>>(x, A0, tf, A1, out);
}

// Round 13
// 71.813 us; speedup vs baseline: 1.0022x; 1.0022x over previous
//
#include <hip/hip_runtime.h>

#define HH 192
#define WW 192
#define BB 2
#define NC 6
#define FSZ 11
#define PAD 5
#define TW 24
#define TH 12
#define HW (HH*WW)

#define S1R 32             // kernel A staged rows = TH + 4*PAD
#define S1C 45             // staged cols = TW + 4*PAD + 1 guard
#define Q1R 22             // intermediate q rows = TH + 2*PAD
#define Q1C 34             // cols = TW + 2*PAD
#define BTA 768            // kernel A threads (12 waves)

#define S3R 22             // kernel B staged rows
#define S3C 35             // staged cols (+1 guard)
#define BTB 576            // kernel B threads (9 waves)

// bf16 pack/unpack (round-half-up)
__device__ __forceinline__ unsigned pkbf(float a, float b) {
    unsigned ua = (__float_as_uint(a) + 0x8000u) >> 16;
    unsigned ub = (__float_as_uint(b) + 0x8000u) & 0xffff0000u;
    return ua | ub;
}
__device__ __forceinline__ float lo16(unsigned u){ return __uint_as_float(u << 16); }
__device__ __forceinline__ float hi16(unsigned u){ return __uint_as_float(u & 0xffff0000u); }

__device__ __forceinline__ void build_sf(int tid, float s0, float s1, float isb,
                                         float swv, float awv, float* sfw, float* sfa)
{
    if (tid < FSZ*FSZ) {
        const int fi = tid / FSZ, fj = tid - (tid/FSZ)*FSZ;
        const float ri = (float)(fi-PAD)*s0*isb;
        const float rj = (float)(fj-PAD)*s1*isb;
        float sf = __expf(-0.5f*(ri*ri+rj*rj));
        if (fi==PAD && fj==PAD) sf = 0.f;
        sfw[tid] = sf*swv;
        sfa[tid] = sf*awv;
    }
}

// ---------------------------------------------------------------------------
// Kernel A: TWO fused mean-field iterations on a 24x12 tile.
//   stage 32x44 (q + prescaled f, halo 10) ->
//   pass 1: 22x34 intermediate q in LDS (1 px/thread, 121 taps) ->
//   pass 2: 12x24 tile (2 thr/px, row-halves, shfl combine) -> packed slab.
// FIRST: staging computes q=softmax(x) from planar x and prescales features;
//        epilogue also writes the f2 slab.
// ---------------------------------------------------------------------------
template<bool FIRST>
__global__ __launch_bounds__(BTA, 3)
void crf_duo(const float* __restrict__ xpl, const uint4* __restrict__ Ain,
             const float* __restrict__ f2in, const float* __restrict__ feats,
             const float* __restrict__ spac, const float* __restrict__ swp,
             const float* __restrict__ awp, const float* __restrict__ isbp,
             const float* __restrict__ iabp,
             uint4* __restrict__ Aout, float* __restrict__ f2out)
{
    __shared__ uint4 A1[S1R][S1C];      // q01,q23,q45,f01 (bf16x2, f prescaled)
    __shared__ float F2a[S1R][S1C];     // f2 (f32, prescaled)
    __shared__ uint4 Q1[Q1R][Q1C];      // pass-1 q output
    __shared__ float sfw[FSZ*FSZ], sfa[FSZ*FSZ];

    const int tid = threadIdx.x;
    const int b  = blockIdx.z;
    const int w0 = blockIdx.x * TW;
    const int h0 = blockIdx.y * TH;

    const float sw = swp[0], aw = awp[0], isb = isbp[0], iab = iabp[0];
    const float s0 = spac[b*2], s1 = spac[b*2+1];
    const float sfac = iab * 0.70710678f;     // af = exp(-sum(d^2)) on prescaled f

    build_sf(tid, s0, s1, isb, sw, aw, sfw, sfa);

    // ---- stage 32 x 45 (zeros outside image) ----
    for (int idx = tid; idx < S1R*S1C; idx += BTA) {
        const int sr = idx / S1C, sc = idx - (idx/S1C)*S1C;
        const int gh = h0 - 2*PAD + sr, gw = w0 - 2*PAD + sc;
        uint4 av = make_uint4(0u,0u,0u,0u);
        float f2v = 0.f;
        if (gh >= 0 && gh < HH && gw >= 0 && gw < WW) {
            if (FIRST) {
                const int off = gh*WW + gw;
                const float* xb = xpl + (size_t)b*NC*HW + off;
                const float v0=xb[0], v1=xb[HW], v2=xb[2*HW];
                const float v3=xb[3*HW], v4=xb[4*HW], v5=xb[5*HW];
                float m = fmaxf(fmaxf(fmaxf(v0,v1),fmaxf(v2,v3)),fmaxf(v4,v5));
                float q0=__expf(v0-m), q1=__expf(v1-m), q2=__expf(v2-m);
                float q3=__expf(v3-m), q4=__expf(v4-m), q5=__expf(v5-m);
                const float rs = 1.0f/(q0+q1+q2+q3+q4+q5);
                const float* fb = feats + (size_t)b*3*HW + off;
                const float g0 = fb[0]*sfac, g1 = fb[HW]*sfac;
                f2v = fb[2*HW]*sfac;
                av = make_uint4(pkbf(q0*rs,q1*rs), pkbf(q2*rs,q3*rs),
                                pkbf(q4*rs,q5*rs), pkbf(g0,g1));
            } else {
                const size_t p = (size_t)(b*HH + gh)*WW + gw;
                av  = Ain[p];
                f2v = f2in[p];
            }
        }
        A1[sr][sc]  = av;
        F2a[sr][sc] = f2v;
    }
    __syncthreads();

    // ---- pass 1: iter k. 1 px/thread over 22x34, full 121-tap loop ----
    if (tid < Q1R*Q1C) {
        const int pr = tid / Q1C, pc = tid - (tid/Q1C)*Q1C;
        const int gh = h0 - PAD + pr, gw = w0 - PAD + pc;
        uint4 qv = make_uint4(0u,0u,0u,0u);
        if (gh >= 0 && gh < HH && gw >= 0 && gw < WW) {
            const unsigned cw = A1[pr+PAD][pc+PAD].w;
            const float cf0 = lo16(cw), cf1 = hi16(cw);
            const float cf2 = F2a[pr+PAD][pc+PAD];
            float msg[NC];
            #pragma unroll
            for (int c = 0; c < NC; ++c) msg[c] = 0.f;
            #pragma unroll 1
            for (int i = 0; i < FSZ; ++i) {
                const float* srw = &sfw[i*FSZ];
                const float* sra = &sfa[i*FSZ];
                #pragma unroll
                for (int j = 0; j < FSZ; ++j) {
                    const uint4 av = A1[pr+i][pc+j];
                    const float g2 = F2a[pr+i][pc+j];
                    const float g0 = lo16(av.w), g1 = hi16(av.w);
                    const float d0 = cf0-g0, d1 = cf1-g1, d2 = cf2-g2;
                    const float t  = fmaf(d2,d2, fmaf(d1,d1, d0*d0));
                    const float tf = fmaf(__expf(-t), sra[j], srw[j]);
                    msg[0] = fmaf(tf, lo16(av.x), msg[0]);
                    msg[1] = fmaf(tf, hi16(av.x), msg[1]);
                    msg[2] = fmaf(tf, lo16(av.y), msg[2]);
                    msg[3] = fmaf(tf, hi16(av.y), msg[3]);
                    msg[4] = fmaf(tf, lo16(av.z), msg[4]);
                    msg[5] = fmaf(tf, hi16(av.z), msg[5]);
                }
            }
            // x_new = unary + msg -> softmax -> pack
            const float* up = xpl + (size_t)b*NC*HW + (size_t)gh*WW + gw;
            float xn[NC];
            #pragma unroll
            for (int c = 0; c < NC; ++c) xn[c] = msg[c] + up[(size_t)c*HW];
            float m = xn[0];
            #pragma unroll
            for (int c = 1; c < NC; ++c) m = fmaxf(m, xn[c]);
            float e[NC], s = 0.f;
            #pragma unroll
            for (int c = 0; c < NC; ++c) { e[c] = __expf(xn[c]-m); s += e[c]; }
            const float rs = 1.0f / s;
            qv = make_uint4(pkbf(e[0]*rs,e[1]*rs), pkbf(e[2]*rs,e[3]*rs),
                            pkbf(e[4]*rs,e[5]*rs), 0u);
        }
        Q1[tid / Q1C][tid - (tid/Q1C)*Q1C] = qv;
    }
    __syncthreads();

    // ---- pass 2: iter k+1. 2 threads/px over 12x24 (row halves) ----
    if (tid < 2*TH*TW) {
        const int p = tid >> 1, h = tid & 1;
        const int qr = p / TW, qc = p - (p/TW)*TW;
        const unsigned cw = A1[qr+2*PAD][qc+2*PAD].w;
        const float cf0 = lo16(cw), cf1 = hi16(cw);
        const float cf2 = F2a[qr+2*PAD][qc+2*PAD];
        float msg[NC];
        #pragma unroll
        for (int c = 0; c < NC; ++c) msg[c] = 0.f;
        const int i0 = h ? 6 : 0, i1 = h ? FSZ : 6;
        #pragma unroll 1
        for (int i = i0; i < i1; ++i) {
            const float* srw = &sfw[i*FSZ];
            const float* sra = &sfa[i*FSZ];
            #pragma unroll
            for (int j = 0; j < FSZ; ++j) {
                const uint4 qv = Q1[qr+i][qc+j];
                const uint4 fv = A1[qr+i+PAD][qc+j+PAD];
                const float g2 = F2a[qr+i+PAD][qc+j+PAD];
                const float g0 = lo16(fv.w), g1 = hi16(fv.w);
                const float d0 = cf0-g0, d1 = cf1-g1, d2 = cf2-g2;
                const float t  = fmaf(d2,d2, fmaf(d1,d1, d0*d0));
                const float tf = fmaf(__expf(-t), sra[j], srw[j]);
                msg[0] = fmaf(tf, lo16(qv.x), msg[0]);
                msg[1] = fmaf(tf, hi16(qv.x), msg[1]);
                msg[2] = fmaf(tf, lo16(qv.y), msg[2]);
                msg[3] = fmaf(tf, hi16(qv.y), msg[3]);
                msg[4] = fmaf(tf, lo16(qv.z), msg[4]);
                msg[5] = fmaf(tf, hi16(qv.z), msg[5]);
            }
        }
        #pragma unroll
        for (int c = 0; c < NC; ++c) msg[c] += __shfl_xor(msg[c], 1);

        if (h == 0) {
            const int oh = h0 + qr, ow = w0 + qc;
            const size_t pb = (size_t)b*NC*HW + (size_t)oh*WW + ow;
            float xn[NC];
            #pragma unroll
            for (int c = 0; c < NC; ++c) xn[c] = msg[c] + xpl[pb + (size_t)c*HW];
            float m = xn[0];
            #pragma unroll
            for (int c = 1; c < NC; ++c) m = fmaxf(m, xn[c]);
            float e[NC], s = 0.f;
            #pragma unroll
            for (int c = 0; c < NC; ++c) { e[c] = __expf(xn[c]-m); s += e[c]; }
            const float rs = 1.0f / s;
            const size_t op = (size_t)(b*HH + oh)*WW + ow;
            Aout[op] = make_uint4(pkbf(e[0]*rs,e[1]*rs), pkbf(e[2]*rs,e[3]*rs),
                                  pkbf(e[4]*rs,e[5]*rs), cw);
            if (FIRST) f2out[op] = cf2;
        }
    }
}

// ---------------------------------------------------------------------------
// Kernel B: final iteration + log_softmax (planar out). 2 thr/px.
// ---------------------------------------------------------------------------
__global__ __launch_bounds__(BTB, 2)
void crf_fin(const float* __restrict__ xpl, const uint4* __restrict__ Ain,
             const float* __restrict__ f2in,
             const float* __restrict__ spac, const float* __restrict__ swp,
             const float* __restrict__ awp, const float* __restrict__ isbp,
             const float* __restrict__ iabp, float* __restrict__ outp)
{
    __shared__ uint4 A[S3R][S3C];
    __shared__ float F2[S3R][S3C];
    __shared__ float sfw[FSZ*FSZ], sfa[FSZ*FSZ];

    const int tid = threadIdx.x;
    const int b  = blockIdx.z;
    const int w0 = blockIdx.x * TW;
    const int h0 = blockIdx.y * TH;

    const float sw = swp[0], aw = awp[0], isb = isbp[0];
    const float s0 = spac[b*2], s1 = spac[b*2+1];

    build_sf(tid, s0, s1, isb, sw, aw, sfw, sfa);

    for (int idx = tid; idx < S3R*S3C; idx += BTB) {
        const int sr = idx / S3C, sc = idx - (idx/S3C)*S3C;
        const int gh = h0 - PAD + sr, gw = w0 - PAD + sc;
        uint4 av = make_uint4(0u,0u,0u,0u);
        float f2v = 0.f;
        if (gh >= 0 && gh < HH && gw >= 0 && gw < WW) {
            const size_t p = (size_t)(b*HH + gh)*WW + gw;
            av  = Ain[p];
            f2v = f2in[p];
        }
        A[sr][sc]  = av;
        F2[sr][sc] = f2v;
    }
    __syncthreads();

    if (tid < 2*TH*TW) {
        const int p = tid >> 1, h = tid & 1;
        const int qr = p / TW, qc = p - (p/TW)*TW;
        const unsigned cw = A[qr+PAD][qc+PAD].w;
        const float cf0 = lo16(cw), cf1 = hi16(cw);
        const float cf2 = F2[qr+PAD][qc+PAD];
        float msg[NC];
        #pragma unroll
        for (int c = 0; c < NC; ++c) msg[c] = 0.f;
        const int i0 = h ? 6 : 0, i1 = h ? FSZ : 6;
        #pragma unroll 1
        for (int i = i0; i < i1; ++i) {
            const float* srw = &sfw[i*FSZ];
            const float* sra = &sfa[i*FSZ];
            #pragma unroll
            for (int j = 0; j < FSZ; ++j) {
                const uint4 qv = A[qr+i][qc+j];
                const float g2 = F2[qr+i][qc+j];
                const float g0 = lo16(qv.w), g1 = hi16(qv.w);
                const float d0 = cf0-g0, d1 = cf1-g1, d2 = cf2-g2;
                const float t  = fmaf(d2,d2, fmaf(d1,d1, d0*d0));
                const float tf = fmaf(__expf(-t), sra[j], srw[j]);
                msg[0] = fmaf(tf, lo16(qv.x), msg[0]);
                msg[1] = fmaf(tf, hi16(qv.x), msg[1]);
                msg[2] = fmaf(tf, lo16(qv.y), msg[2]);
                msg[3] = fmaf(tf, hi16(qv.y), msg[3]);
                msg[4] = fmaf(tf, lo16(qv.z), msg[4]);
                msg[5] = fmaf(tf, hi16(qv.z), msg[5]);
            }
        }
        #pragma unroll
        for (int c = 0; c < NC; ++c) msg[c] += __shfl_xor(msg[c], 1);

        if (h == 0) {
            const int oh = h0 + qr, ow = w0 + qc;
            const size_t pb = (size_t)b*NC*HW + (size_t)oh*WW + ow;
            float xn[NC];
            #pragma unroll
            for (int c = 0; c < NC; ++c) xn[c] = msg[c] + xpl[pb + (size_t)c*HW];
            float m = xn[0];
            #pragma unroll
            for (int c = 1; c < NC; ++c) m = fmaxf(m, xn[c]);
            float s = 0.f;
            #pragma unroll
            for (int c = 0; c < NC; ++c) s += __expf(xn[c]-m);
            const float lg = m + __logf(s);
            #pragma unroll
            for (int c = 0; c < NC; ++c) outp[pb + (size_t)c*HW] = xn[c] - lg;
        }
    }
}

extern "C" void kernel_launch(void* const* d_in, const int* in_sizes, int n_in,
                              void* d_out, int out_size, void* d_ws, size_t ws_size,
                              hipStream_t stream)
{
    const float* x    = (const float*)d_in[0];
    const float* fts  = (const float*)d_in[1];
    const float* spc  = (const float*)d_in[2];
    const float* swp  = (const float*)d_in[3];
    const float* awp  = (const float*)d_in[4];
    const float* isbp = (const float*)d_in[5];
    const float* iabp = (const float*)d_in[6];
    float* out = (float*)d_out;

    uint4* S0  = (uint4*)d_ws;                     // q after iter 2
    uint4* S1  = S0 + (size_t)BB*HW;               // q after iter 4
    float* f2s = (float*)(S1 + (size_t)BB*HW);     // prescaled f2 slab

    dim3 grid(WW/TW, HH/TH, BB);   // 8 x 16 x 2 = 256 blocks = 1 per CU

    // iters 1+2 -> S0 ; iters 3+4 -> S1 ; iter 5 -> out (log_softmax)
    crf_duo<true ><<<grid, dim3(BTA), 0, stream>>>(x, S1, f2s, fts, spc, swp, awp, isbp, iabp, S0, f2s);
    crf_duo<false><<<grid, dim3(BTA), 0, stream>>>(x, S0, f2s, fts, spc, swp, awp, isbp, iabp, S1, f2s);
    crf_fin<<<grid, dim3(BTB), 0, stream>>>(x, S1, f2s, spc, swp, awp, isbp, iabp, out);
}